// Round 1
// baseline (272.803 us; speedup 1.0000x reference)
//
#include <hip/hip_runtime.h>

// Problem constants
#define IH 4096
#define IW 4096
#define KH 11
#define KW 11
#define OH (IH - KH + 1)   // 4086
#define OW (IW - KW + 1)   // 4086

// Tiling
#define BM 64              // output tile rows per block
#define BN 64              // output tile cols per block
#define TM 4               // outputs per thread (rows)
#define TN 4               // outputs per thread (cols)
#define TX 16              // threads in x (TX*TN = BN)
#define TY 16              // threads in y (TY*TM = BM)
#define LDS_H (BM + KH - 1)        // 74 input rows
#define LDS_W_REAL (BN + KW - 1)   // 74 input cols needed
#define LDS_W 76                   // padded row stride (floats), 16B-aligned rows
#define NCHUNK (LDS_H * (LDS_W / 4))  // float4 chunks to stage = 74*19 = 1406

__global__ __launch_bounds__(256)
void conv2d_f32_tile(const float* __restrict__ x,
                     const float* __restrict__ w,
                     const float* __restrict__ bias,
                     float* __restrict__ out) {
    __shared__ float tile[LDS_H * LDS_W];   // 74*76*4 = 22496 B

    const int tid = threadIdx.x;
    const int gx0 = blockIdx.x * BN;        // first output col of this tile
    const int gy0 = blockIdx.y * BM;        // first output row of this tile

    // ---- Stage input halo tile (74 x 74, padded to 76) into LDS ----
    // Chunk i covers LDS row i/19, float4 group i%19.
    // gx0 is a multiple of 64 -> global float4 loads are 16B aligned.
    // Cols/rows past the image are zero-filled; they feed only outputs that
    // are themselves guarded out of range.
#pragma unroll
    for (int i = tid; i < NCHUNK; i += TX * TY) {
        const int r  = i / (LDS_W / 4);
        const int c4 = i - r * (LDS_W / 4);
        const int gy = gy0 + r;
        const int gx = gx0 + c4 * 4;
        float4 v = make_float4(0.f, 0.f, 0.f, 0.f);
        if (gy < IH && gx + 3 < IW) {
            v = *reinterpret_cast<const float4*>(x + (size_t)gy * IW + gx);
        }
        *reinterpret_cast<float4*>(&tile[r * LDS_W + c4 * 4]) = v;
    }
    __syncthreads();

    // ---- Compute 4x4 outputs per thread ----
    const int tx = tid & (TX - 1);
    const int ty = tid >> 4;
    const int lx = tx * TN;    // local output col
    const int ly = ty * TM;    // local output row

    float acc[TM][TN] = {};

    // Stream 14 input rows; each contributes to up to TM output rows.
#pragma unroll
    for (int r = 0; r < TM + KH - 1; ++r) {     // 14 rows
        const float* src = &tile[(ly + r) * LDS_W + lx];  // 16B aligned
        float xv[TN + KW - 1];                   // 14 floats
        {
            float4 a = *reinterpret_cast<const float4*>(src);
            float4 b = *reinterpret_cast<const float4*>(src + 4);
            float4 c = *reinterpret_cast<const float4*>(src + 8);
            float2 d = *reinterpret_cast<const float2*>(src + 12);
            xv[0]=a.x;  xv[1]=a.y;  xv[2]=a.z;  xv[3]=a.w;
            xv[4]=b.x;  xv[5]=b.y;  xv[6]=b.z;  xv[7]=b.w;
            xv[8]=c.x;  xv[9]=c.y;  xv[10]=c.z; xv[11]=c.w;
            xv[12]=d.x; xv[13]=d.y;
        }
#pragma unroll
        for (int ry = 0; ry < TM; ++ry) {
            const int kh = r - ry;               // compile-time constant
            if (kh >= 0 && kh < KH) {
#pragma unroll
                for (int kw = 0; kw < KW; ++kw) {
                    const float wv = w[kh * KW + kw];  // uniform -> s_load
#pragma unroll
                    for (int rx = 0; rx < TN; ++rx) {
                        acc[ry][rx] = fmaf(xv[kw + rx], wv, acc[ry][rx]);
                    }
                }
            }
        }
    }

    // ---- Write back (8B-aligned float2 stores; OW=4086 is even) ----
    const float bv = bias[0];
    const int ox = gx0 + lx;
#pragma unroll
    for (int ry = 0; ry < TM; ++ry) {
        const int oy = gy0 + ly + ry;
        if (oy < OH) {
            const size_t base = (size_t)oy * OW + ox;
            if (ox + TN - 1 < OW) {
                float2 p0 = make_float2(acc[ry][0] + bv, acc[ry][1] + bv);
                float2 p1 = make_float2(acc[ry][2] + bv, acc[ry][3] + bv);
                *reinterpret_cast<float2*>(out + base)     = p0;
                *reinterpret_cast<float2*>(out + base + 2) = p1;
            } else {
#pragma unroll
                for (int rx = 0; rx < TN; ++rx) {
                    if (ox + rx < OW) out[base + rx] = acc[ry][rx] + bv;
                }
            }
        }
    }
}

extern "C" void kernel_launch(void* const* d_in, const int* in_sizes, int n_in,
                              void* d_out, int out_size, void* d_ws, size_t ws_size,
                              hipStream_t stream) {
    const float* x    = (const float*)d_in[0];
    const float* w    = (const float*)d_in[1];
    const float* bias = (const float*)d_in[2];
    float* out        = (float*)d_out;

    dim3 grid((OW + BN - 1) / BN, (OH + BM - 1) / BM);  // 64 x 64
    dim3 block(TX * TY);                                 // 256
    conv2d_f32_tile<<<grid, block, 0, stream>>>(x, w, bias, out);
}

// Round 2
// 205.502 us; speedup vs baseline: 1.3275x; 1.3275x over previous
//
#include <hip/hip_runtime.h>

// Problem constants
#define IH 4096
#define IW 4096
#define KH 11
#define KW 11
#define OH (IH - KH + 1)   // 4086
#define OW (IW - KW + 1)   // 4086

// Tiling
#define BM 64              // output tile rows per block
#define BN 64              // output tile cols per block
#define TM 4               // outputs per thread (rows)
#define TN 4               // outputs per thread (cols)
#define TX 16              // threads in x
#define TY 16              // threads in y
#define LDS_H (BM + KH - 1)        // 74 input rows
#define LDS_W 76                   // padded row stride (floats); 74 needed
#define NCHUNK (LDS_H * (LDS_W / 4))  // 74*19 = 1406 float4 chunks
#define NITER  ((NCHUNK + 255) / 256) // 6 staging iterations

__global__ __launch_bounds__(256)
void conv2d_f32_tile(const float* __restrict__ x,
                     const float* __restrict__ w,
                     const float* __restrict__ bias,
                     float* __restrict__ out) {
    __shared__ float tile[LDS_H * LDS_W];   // 22496 B

    const int tid = threadIdx.x;
    const int gx0 = blockIdx.x * BN;
    const int gy0 = blockIdx.y * BM;

    // ---- Stage 74x74 halo tile (rows padded to 76 floats) ----
#pragma unroll
    for (int it = 0; it < NITER; ++it) {
        const int i = tid + it * 256;
        if (i < NCHUNK) {
            const int r  = i / (LDS_W / 4);
            const int c4 = i - r * (LDS_W / 4);
            const int gy = gy0 + r;
            const int gx = gx0 + c4 * 4;
            float4 v = make_float4(0.f, 0.f, 0.f, 0.f);
            if (gy < IH && gx + 3 < IW) {
                v = *reinterpret_cast<const float4*>(x + (size_t)gy * IW + gx);
            }
            *reinterpret_cast<float4*>(&tile[r * LDS_W + c4 * 4]) = v;
        }
    }
    __syncthreads();

    const int tx = tid & (TX - 1);
    const int ty = tid >> 4;
    const int lx = tx * TN;
    const int ly = ty * TM;

    float acc[TM][TN] = {};

    // Rotating weight rows: only 4 rows (<=48 scalars) live at a time.
    // Uniform indices -> these live in SGPRs, not VGPRs.
    float wr[4][KW];

    // r = input row offset within this thread's 4-row output strip.
#pragma unroll
    for (int r = 0; r < TM + KH - 1; ++r) {     // 14 iterations
        // Load weight row r into rotation slot r&3 (compile-time index).
        if (r < KH) {
#pragma unroll
            for (int kw = 0; kw < KW; ++kw) wr[r & 3][kw] = w[r * KW + kw];
        }

        // Load 16 floats of input row (ly + r): 4x ds_read_b128, 16B aligned.
        float xv[16];
        {
            const float4* src =
                reinterpret_cast<const float4*>(&tile[(ly + r) * LDS_W + lx]);
            float4 a = src[0], b = src[1], c = src[2], d = src[3];
            xv[0]=a.x;  xv[1]=a.y;  xv[2]=a.z;  xv[3]=a.w;
            xv[4]=b.x;  xv[5]=b.y;  xv[6]=b.z;  xv[7]=b.w;
            xv[8]=c.x;  xv[9]=c.y;  xv[10]=c.z; xv[11]=c.w;
            xv[12]=d.x; xv[13]=d.y; xv[14]=d.z; xv[15]=d.w;
        }

#pragma unroll
        for (int ry = 0; ry < TM; ++ry) {
            const int kh = r - ry;               // compile-time
            if (kh >= 0 && kh < KH) {
#pragma unroll
                for (int kw = 0; kw < KW; ++kw) {
                    const float wv = wr[kh & 3][kw];
#pragma unroll
                    for (int rx = 0; rx < TN; ++rx) {
                        acc[ry][rx] = fmaf(xv[kw + rx], wv, acc[ry][rx]);
                    }
                }
            }
        }
        // Fence: keep weight loads / row reads inside their iteration so the
        // scheduler can't hoist 121 scalar loads to the top (round-0 failure:
        // SGPR overflow -> VGPR spill -> 252 VGPRs -> 11% occupancy).
        __builtin_amdgcn_sched_barrier(0);
    }

    // ---- Write back ----
    const float bv = bias[0];
    const int ox = gx0 + lx;
#pragma unroll
    for (int ry = 0; ry < TM; ++ry) {
        const int oy = gy0 + ly + ry;
        if (oy < OH) {
            const size_t base = (size_t)oy * OW + ox;
            if (ox + TN - 1 < OW) {
                float2 p0 = make_float2(acc[ry][0] + bv, acc[ry][1] + bv);
                float2 p1 = make_float2(acc[ry][2] + bv, acc[ry][3] + bv);
                *reinterpret_cast<float2*>(out + base)     = p0;
                *reinterpret_cast<float2*>(out + base + 2) = p1;
            } else {
#pragma unroll
                for (int rx = 0; rx < TN; ++rx) {
                    if (ox + rx < OW) out[base + rx] = acc[ry][rx] + bv;
                }
            }
        }
    }
}

extern "C" void kernel_launch(void* const* d_in, const int* in_sizes, int n_in,
                              void* d_out, int out_size, void* d_ws, size_t ws_size,
                              hipStream_t stream) {
    const float* x    = (const float*)d_in[0];
    const float* w    = (const float*)d_in[1];
    const float* bias = (const float*)d_in[2];
    float* out        = (float*)d_out;

    dim3 grid((OW + BN - 1) / BN, (OH + BM - 1) / BM);  // 64 x 64
    dim3 block(TX * TY);                                 // 256
    conv2d_f32_tile<<<grid, block, 0, stream>>>(x, w, bias, out);
}